// Round 11
// baseline (270.962 us; speedup 1.0000x reference)
//
#include <hip/hip_runtime.h>
#include <cstdint>
#include <cstddef>

#define DEV __device__ __forceinline__

typedef __bf16 bf16x8 __attribute__((ext_vector_type(8)));
typedef float f32x4 __attribute__((ext_vector_type(4)));
typedef unsigned short ushort8v __attribute__((ext_vector_type(8)));

DEV ushort f2b(float f) {
  uint u = __float_as_uint(f);
  return (ushort)((u + 0x7FFFu + ((u >> 16) & 1u)) >> 16);
}

DEV float4 shfl_xor4(float4 v, int m) {
  float4 r;
  r.x = __shfl_xor(v.x, m); r.y = __shfl_xor(v.y, m);
  r.z = __shfl_xor(v.z, m); r.w = __shfl_xor(v.w, m);
  return r;
}

DEV float4 unpack4(uint2 u) {
  float4 r;
  r.x = __uint_as_float(u.x << 16);
  r.y = __uint_as_float(u.x & 0xFFFF0000u);
  r.z = __uint_as_float(u.y << 16);
  r.w = __uint_as_float(u.y & 0xFFFF0000u);
  return r;
}

DEV void fma4(float4& a, float w, uint2 u) {
  float4 v = unpack4(u);
  a.x = fmaf(w, v.x, a.x); a.y = fmaf(w, v.y, a.y);
  a.z = fmaf(w, v.z, a.z); a.w = fmaf(w, v.w, a.w);
}

// ===== kernel 1: gemm blocks (bx >= nCB) + degree-count blocks (bx < nCB) ====
// Gemm: 256 thr = 4 waves, 1 row-tile (16 rows) per wave, x fp32 read once,
// W_m fp32->bf16 into 32KB LDS per m-phase, XOR-swizzled (byte ^= (row&7)<<4)
// for conflict-free ds_read_b128 B-fragments. LDS 32KB -> 5 blocks/CU.
__global__ __launch_bounds__(256) void k_gemm_count(
    const float* __restrict__ x,
    const float* __restrict__ W0, const float* __restrict__ W1,
    const float* __restrict__ W2,
    const float* __restrict__ b_hp, const float* __restrict__ b_lp,
    const float* __restrict__ b_i,
    ushort* __restrict__ h_all, int N,
    const int* __restrict__ col, int* __restrict__ cnt, int E, int nCB) {
  __shared__ ushort Wl[16384];
  int tid = (int)threadIdx.x;
  int bx = (int)blockIdx.x;

  if (bx < nCB) {  // ---- count blocks: scheduled first, overlap gemm ----
    int gsz = nCB * 256;
    for (int e = bx * 256 + tid; e < E; e += gsz)
      atomicAdd(&cnt[col[e]], 1);
    return;
  }
  bx -= nCB;

  int lane = tid & 63, wv = tid >> 6;
  int r = lane & 15, g = lane >> 4;
  int NT = N >> 4;
  int t = bx * 4 + wv;
  bool active = t < NT;

  // A-frags: x rows t*16+r, fp32 -> bf16 in-register; persist across all 3 m.
  bf16x8 Af[4];
  if (active) {
    const float* xp = x + ((size_t)t * 16 + r) * 128 + g * 8;
#pragma unroll
    for (int kc = 0; kc < 4; ++kc) {
      float4 v0 = *(const float4*)(xp + kc * 32);
      float4 v1 = *(const float4*)(xp + kc * 32 + 4);
      ushort8v u;
      u[0] = f2b(v0.x); u[1] = f2b(v0.y); u[2] = f2b(v0.z); u[3] = f2b(v0.w);
      u[4] = f2b(v1.x); u[5] = f2b(v1.y); u[6] = f2b(v1.z); u[7] = f2b(v1.w);
      Af[kc] = __builtin_bit_cast(bf16x8, u);
    }
  }

  for (int m = 0; m < 3; ++m) {
    const float* Wsrc = (m == 0) ? W0 : (m == 1) ? W1 : W2;
    __syncthreads();
    // stage W_m: fp32 -> bf16, swizzled, 2048 x 16B chunks / 256 thr = 8 iters
    for (int i = tid; i < 2048; i += 256) {
      int byte = i << 4;
      int row = byte >> 8;
      int swz = byte ^ ((row & 7) << 4);
      const float* s = Wsrc + (i << 3);
      float4 v0 = *(const float4*)s;
      float4 v1 = *(const float4*)(s + 4);
      ushort8v u;
      u[0] = f2b(v0.x); u[1] = f2b(v0.y); u[2] = f2b(v0.z); u[3] = f2b(v0.w);
      u[4] = f2b(v1.x); u[5] = f2b(v1.y); u[6] = f2b(v1.z); u[7] = f2b(v1.w);
      *(ushort8v*)((char*)Wl + swz) = u;
    }
    __syncthreads();
    if (!active) continue;
    const float* bias = (m == 0) ? b_hp : (m == 1) ? b_lp : b_i;
    f32x4 acc[8];
#pragma unroll
    for (int ct = 0; ct < 8; ++ct) {
      float bb = bias[ct * 16 + r];
      f32x4 c; c[0] = bb; c[1] = bb; c[2] = bb; c[3] = bb;
      acc[ct] = c;
    }
#pragma unroll
    for (int kc = 0; kc < 4; ++kc)
#pragma unroll
      for (int ct = 0; ct < 8; ++ct) {
        int row = ct * 16 + r;
        int byte = row * 256 + kc * 64 + g * 16;
        int swz = byte ^ ((row & 7) << 4);
        bf16x8 B = *(const bf16x8*)((const char*)Wl + swz);
        acc[ct] = __builtin_amdgcn_mfma_f32_16x16x32_bf16(Af[kc], B, acc[ct], 0, 0, 0);
      }
    ushort* op = h_all + (size_t)(t * 16 + g * 4) * 384 + m * 128 + r;
#pragma unroll
    for (int ct = 0; ct < 8; ++ct)
#pragma unroll
      for (int j = 0; j < 4; ++j) {
        float v = acc[ct][j];
        if (m == 2) v = fmaxf(v, 0.f);
        op[(size_t)j * 384 + ct * 16] = f2b(v);
      }
  }
}

// ---------------- scan phase A: per-256-chunk scan + dinv ----------------
__global__ __launch_bounds__(256) void k_scanA(const int* __restrict__ cnt,
                                               int* __restrict__ off,
                                               float* __restrict__ dinv,
                                               int* __restrict__ btot, int N) {
  __shared__ int ws[4];
  int t = threadIdx.x, ln = t & 63, wv = t >> 6;
  int i = blockIdx.x * 256 + t;
  int v = (i < N) ? cnt[i] : 0;
  int inc = v;
#pragma unroll
  for (int o = 1; o < 64; o <<= 1) {
    int u = __shfl_up(inc, o);
    if (ln >= o) inc += u;
  }
  if (ln == 63) ws[wv] = inc;
  __syncthreads();
  if (t == 0) {
    int s = 0;
#pragma unroll
    for (int w = 0; w < 4; ++w) { int tmp = ws[w]; ws[w] = s; s += tmp; }
  }
  __syncthreads();
  int excl = ws[wv] + inc - v;
  if (i < N) {
    off[i] = excl;
    dinv[i] = rsqrtf((float)v + 1.0f);
  }
  if (t == 255) btot[blockIdx.x] = excl + v;
}

// -------- scan phase B+C fused: every block rescans btot, applies prefix ----
__global__ __launch_bounds__(256) void k_scanBC(int* __restrict__ off,
                                                const int* __restrict__ btot,
                                                int* __restrict__ cursor,
                                                int N, int E, int NB) {
  __shared__ int ws[4];
  __shared__ int pre_sh[256];
  int t = threadIdx.x, ln = t & 63, wv = t >> 6;
  int v = (t < NB) ? btot[t] : 0;
  int inc = v;
#pragma unroll
  for (int o = 1; o < 64; o <<= 1) {
    int u = __shfl_up(inc, o);
    if (ln >= o) inc += u;
  }
  if (ln == 63) ws[wv] = inc;
  __syncthreads();
  if (t == 0) {
    int s = 0;
#pragma unroll
    for (int w = 0; w < 4; ++w) { int tmp = ws[w]; ws[w] = s; s += tmp; }
  }
  __syncthreads();
  pre_sh[t] = ws[wv] + inc - v;
  __syncthreads();
  int bpre = pre_sh[blockIdx.x];
  int i = blockIdx.x * 256 + t;
  if (i < N) {
    int o = off[i] + bpre;
    off[i] = o;
    cursor[i] = o;
  }
  if (blockIdx.x == 0 && t == 0) off[N] = E;
}

// -------- scatter edges into CSR; payload = (src, dinv[src]) --------
__global__ __launch_bounds__(256) void k_scatter(const int* __restrict__ ei,
                                                 const float* __restrict__ dinv,
                                                 int* __restrict__ cursor,
                                                 int2* __restrict__ edata, int E) {
  int e = blockIdx.x * 256 + threadIdx.x;
  if (e >= E) return;
  int s = ei[e], d = ei[E + e];
  float ws = dinv[s];
  int p = atomicAdd(&cursor[d], 1);
  int2 v; v.x = s; v.y = __float_as_int(ws);
  edata[p] = v;
}

// ========== fused aggregation + epilogue (wave/node, 8 gathers in flight) ===
// h_all row: [0:128]=h_hp, [128:256]=h_lp, [256:384]=H_i (bf16).
// Edge weights: acc = sum dinv[s]*h[s]; full agg = dinv[d]*(acc + dinv[d]*self).
__global__ __launch_bounds__(256) void k_agg_final(
    const ushort* __restrict__ h_all, const float* __restrict__ dinv,
    const int* __restrict__ off, const int2* __restrict__ edata,
    const float* __restrict__ wlh, const float* __restrict__ wll,
    const float* __restrict__ wli,
    const float* __restrict__ pbh, const float* __restrict__ pbl,
    const float* __restrict__ pbi,
    float* __restrict__ out, int N) {
  int wv = __builtin_amdgcn_readfirstlane((int)threadIdx.x >> 6);
  int lane = (int)threadIdx.x & 63;
  int node = blockIdx.x * 4 + wv;
  if (node >= N) return;

  const ushort* hb = h_all + 4 * lane;  // + s*384 per edge
  int p0 = off[node], p1 = off[node + 1];

  float4 a0 = {0,0,0,0}, a1 = {0,0,0,0}, a2 = {0,0,0,0}, a3 = {0,0,0,0};
  float4 a4 = {0,0,0,0}, a5 = {0,0,0,0}, a6 = {0,0,0,0}, a7 = {0,0,0,0};
  int p = p0;
  for (; p + 8 <= p1; p += 8) {
    int2 e0 = edata[p],     e1 = edata[p + 1], e2 = edata[p + 2], e3 = edata[p + 3];
    int2 e4 = edata[p + 4], e5 = edata[p + 5], e6 = edata[p + 6], e7 = edata[p + 7];
    uint2 u0 = *(const uint2*)(const void*)(hb + (size_t)e0.x * 384);
    uint2 u1 = *(const uint2*)(const void*)(hb + (size_t)e1.x * 384);
    uint2 u2 = *(const uint2*)(const void*)(hb + (size_t)e2.x * 384);
    uint2 u3 = *(const uint2*)(const void*)(hb + (size_t)e3.x * 384);
    uint2 u4 = *(const uint2*)(const void*)(hb + (size_t)e4.x * 384);
    uint2 u5 = *(const uint2*)(const void*)(hb + (size_t)e5.x * 384);
    uint2 u6 = *(const uint2*)(const void*)(hb + (size_t)e6.x * 384);
    uint2 u7 = *(const uint2*)(const void*)(hb + (size_t)e7.x * 384);
    fma4(a0, __int_as_float(e0.y), u0);
    fma4(a1, __int_as_float(e1.y), u1);
    fma4(a2, __int_as_float(e2.y), u2);
    fma4(a3, __int_as_float(e3.y), u3);
    fma4(a4, __int_as_float(e4.y), u4);
    fma4(a5, __int_as_float(e5.y), u5);
    fma4(a6, __int_as_float(e6.y), u6);
    fma4(a7, __int_as_float(e7.y), u7);
  }
  for (; p < p1; ++p) {
    int2 e = edata[p];
    uint2 u = *(const uint2*)(const void*)(hb + (size_t)e.x * 384);
    fma4(a0, __int_as_float(e.y), u);
  }
  float4 own;
  own.x = ((a0.x + a1.x) + (a2.x + a3.x)) + ((a4.x + a5.x) + (a6.x + a7.x));
  own.y = ((a0.y + a1.y) + (a2.y + a3.y)) + ((a4.y + a5.y) + (a6.y + a7.y));
  own.z = ((a0.z + a1.z) + (a2.z + a3.z)) + ((a4.z + a5.z) + (a6.z + a7.z));
  own.w = ((a0.w + a1.w) + (a2.w + a3.w)) + ((a4.w + a5.w) + (a6.w + a7.w));

  // fold symmetric normalization: agg = di*(sum + di*self)
  float di = dinv[node];
  float4 sv = unpack4(*(const uint2*)(const void*)(hb + (size_t)node * 384));
  own.x = (own.x + di * sv.x) * di; own.y = (own.y + di * sv.y) * di;
  own.z = (own.z + di * sv.z) * di; own.w = (own.w + di * sv.w) * di;

  // exchange halves: lanes<32 hold hp-side, lanes>=32 hold lp-side (same cols)
  float4 oth = shfl_xor4(own, 32);
  float4 svo = shfl_xor4(sv, 32);
  bool hpside = (lane < 32);
  float4 hpSelf, aggHp, aggLp;
  hpSelf.x = hpside ? sv.x : svo.x; hpSelf.y = hpside ? sv.y : svo.y;
  hpSelf.z = hpside ? sv.z : svo.z; hpSelf.w = hpside ? sv.w : svo.w;
  aggHp.x = hpside ? own.x : oth.x; aggHp.y = hpside ? own.y : oth.y;
  aggHp.z = hpside ? own.z : oth.z; aggHp.w = hpside ? own.w : oth.w;
  aggLp.x = hpside ? oth.x : own.x; aggLp.y = hpside ? oth.y : own.y;
  aggLp.z = hpside ? oth.z : own.z; aggLp.w = hpside ? oth.w : own.w;

  float4 Hh, Hl;
  Hh.x = fmaxf(hpSelf.x - aggHp.x, 0.f); Hh.y = fmaxf(hpSelf.y - aggHp.y, 0.f);
  Hh.z = fmaxf(hpSelf.z - aggHp.z, 0.f); Hh.w = fmaxf(hpSelf.w - aggHp.w, 0.f);
  Hl.x = fmaxf(aggLp.x, 0.f); Hl.y = fmaxf(aggLp.y, 0.f);
  Hl.z = fmaxf(aggLp.z, 0.f); Hl.w = fmaxf(aggLp.w, 0.f);

  int c4 = 4 * (lane & 31);
  float4 hi4 = unpack4(*(const uint2*)(const void*)(h_all + (size_t)node * 384 + 256 + c4));
  float4 wh = *(const float4*)(wlh + c4);
  float4 wl = *(const float4*)(wll + c4);
  float4 wi = *(const float4*)(wli + c4);

  float dh = Hh.x * wh.x + Hh.y * wh.y + Hh.z * wh.z + Hh.w * wh.w;
  float dl = Hl.x * wl.x + Hl.y * wl.y + Hl.z * wl.z + Hl.w * wl.w;
  float dd = hi4.x * wi.x + hi4.y * wi.y + hi4.z * wi.z + hi4.w * wi.w;
#pragma unroll
  for (int o = 32; o > 0; o >>= 1) {
    dh += __shfl_xor(dh, o);
    dl += __shfl_xor(dl, o);
    dd += __shfl_xor(dd, o);
  }
  // each column counted twice (both half-waves) -> x0.5
  float a_h = 1.f / (1.f + __expf(-(0.5f * dh + pbh[0])));
  float a_l = 1.f / (1.f + __expf(-(0.5f * dl + pbl[0])));
  float a_i = 1.f / (1.f + __expf(-(0.5f * dd + pbi[0])));

  if (hpside) {
    float4 o4;
    o4.x = a_h * Hh.x + a_l * Hl.x + a_i * hi4.x;
    o4.y = a_h * Hh.y + a_l * Hl.y + a_i * hi4.y;
    o4.z = a_h * Hh.z + a_l * Hl.z + a_i * hi4.z;
    o4.w = a_h * Hh.w + a_l * Hl.w + a_i * hi4.w;
    *(float4*)(out + (size_t)node * 128 + c4) = o4;
  }
}

// ================= launch ===================================================
extern "C" void kernel_launch(void* const* d_in, const int* in_sizes, int n_in,
                              void* d_out, int out_size, void* d_ws, size_t ws_size,
                              hipStream_t stream) {
  const float* x     = (const float*)d_in[0];
  const int*   ei    = (const int*)d_in[1];
  const float* W_hp  = (const float*)d_in[2];
  const float* b_hp  = (const float*)d_in[3];
  const float* W_lp  = (const float*)d_in[4];
  const float* b_lp  = (const float*)d_in[5];
  const float* W_i   = (const float*)d_in[6];
  const float* b_i   = (const float*)d_in[7];
  const float* wlh   = (const float*)d_in[8];
  const float* pbh   = (const float*)d_in[9];
  const float* wll   = (const float*)d_in[10];
  const float* pbl   = (const float*)d_in[11];
  const float* wli   = (const float*)d_in[12];
  const float* pbi   = (const float*)d_in[13];
  float* out = (float*)d_out;

  int N = in_sizes[0] / 128;
  int E = in_sizes[1] / 2;
  int NB = (N + 255) / 256;

  ushort* h_all = (ushort*)d_ws;                    // N*384
  int2*   edata = (int2*)(h_all + (size_t)N * 384); // E
  float*  dinv  = (float*)(edata + E);              // N
  int*    cnt   = (int*)(dinv + N);                 // N
  int*    off   = cnt + N;                          // N+1
  int*    cursor= off + N + 1;                      // N
  int*    btot  = cursor + N;                       // 256

  int nGB = (N / 16 + 3) / 4;   // gemm blocks (4 row-tiles each)
  int nCB = 782;                // count blocks (grid-stride over E)

  hipMemsetAsync(cnt, 0, sizeof(int) * N, stream);
  k_gemm_count<<<nCB + nGB, 256, 0, stream>>>(
      x, W_hp, W_lp, W_i, b_hp, b_lp, b_i, h_all, N, ei + E, cnt, E, nCB);
  k_scanA<<<NB, 256, 0, stream>>>(cnt, off, dinv, btot, N);
  k_scanBC<<<NB, 256, 0, stream>>>(off, btot, cursor, N, E, NB);
  k_scatter<<<(E + 255) / 256, 256, 0, stream>>>(ei, dinv, cursor, edata, E);
  k_agg_final<<<(N + 3) / 4, 256, 0, stream>>>(
      h_all, dinv, off, edata, wlh, wll, wli, pbh, pbl, pbi, out, N);
}